// Round 4
// baseline (225.951 us; speedup 1.0000x reference)
//
#include <hip/hip_runtime.h>
#include <cstdint>

// out[s,b,m,n] = sum_k (x+66)*0.03 * (y-160)*0.025,  S=7 B=8 M=K=N=1024
// y' = y-128; x, y' are exact int8. i8 MFMA (int32-exact):
//   out = 7.5e-4 * ( S' - 32*Rx[m] + 66*Cy[n] - 10813440 ),  S' = sum x*y'
// GEMM: 128x128 tile, 4 waves, BK=64B, 4-deep multibuffer, counted vmcnt(8),
// one barrier/K-step, bijective XOR swizzle key=(row>>1)&3 (conflict-free b128).

#define NG 56

typedef int v4i  __attribute__((ext_vector_type(4)));
typedef int v16i __attribute__((ext_vector_type(16)));

#define GLOAD16(g, l) __builtin_amdgcn_global_load_lds( \
    (const __attribute__((address_space(1))) void*)(g), \
    (__attribute__((address_space(3))) void*)(l), 16, 0, 0)

__device__ __forceinline__ unsigned pack4(float4 v, float& s) {
    s += (v.x + v.y) + (v.z + v.w);
    unsigned b0 = __float_as_uint(v.x + 8388736.0f);  // 2^23 + 128
    unsigned b1 = __float_as_uint(v.y + 8388736.0f);
    unsigned b2 = __float_as_uint(v.z + 8388736.0f);
    unsigned b3 = __float_as_uint(v.w + 8388736.0f);
    return ((b0 & 0xFFu) | ((b1 & 0xFFu) << 8) | ((b2 & 0xFFu) << 16) | ((b3 & 0xFFu) << 24))
           ^ 0x80808080u;
}

// ---- prepass 1: x -> i8 + row sums ----
__global__ __launch_bounds__(256) void k_prep_x(const float* __restrict__ x,
                                                unsigned char* __restrict__ xb,
                                                float* __restrict__ rx) {
    int row  = blockIdx.x * 4 + (threadIdx.x >> 6);
    int lane = threadIdx.x & 63;
    const float* src = x + (size_t)row * 1024;
    float s = 0.f;
#pragma unroll
    for (int it = 0; it < 4; ++it) {
        float4 v = *(const float4*)(src + it * 256 + lane * 4);
        unsigned p = pack4(v, s);
        *(unsigned*)&xb[(size_t)row * 1024 + it * 256 + lane * 4] = p;
    }
#pragma unroll
    for (int off = 32; off > 0; off >>= 1) s += __shfl_down(s, off);
    if (lane == 0) rx[row] = s;
}

// ---- prepass 2: y [b][k][n] -> yt [b][n][k] i8 (= y-128), + col sums Cy ----
__global__ __launch_bounds__(256) void k_prep_y(const float* __restrict__ y,
                                                unsigned char* __restrict__ yt,
                                                float* __restrict__ cy) {
    __shared__ float tile[64][65];
    __shared__ float csum[4][64];
    int b  = blockIdx.x >> 8;
    int t  = blockIdx.x & 255;
    int kt = (t >> 4) * 64, nt = (t & 15) * 64;
    int tx = threadIdx.x & 63;
    int ty = threadIdx.x >> 6;
    const float* src = y + ((size_t)b << 20) + (size_t)kt * 1024 + nt;
    float part = 0.f;
#pragma unroll
    for (int r = 0; r < 16; ++r) {
        int kk = r * 4 + ty;
        float v = src[(size_t)kk * 1024 + tx];
        tile[kk][tx] = v;
        part += v;
    }
    csum[ty][tx] = part;
    __syncthreads();
    if (threadIdx.x < 64) {
        float s = csum[0][tx] + csum[1][tx] + csum[2][tx] + csum[3][tx];
        atomicAdd(&cy[b * 1024 + nt + tx], s);
    }
    int ky = threadIdx.x & 15;
    int ny = threadIdx.x >> 4;
#pragma unroll
    for (int r = 0; r < 4; ++r) {
        int nn = r * 16 + ny;
        unsigned b0 = __float_as_uint(tile[ky * 4 + 0][nn] + 8388608.0f);
        unsigned b1 = __float_as_uint(tile[ky * 4 + 1][nn] + 8388608.0f);
        unsigned b2 = __float_as_uint(tile[ky * 4 + 2][nn] + 8388608.0f);
        unsigned b3 = __float_as_uint(tile[ky * 4 + 3][nn] + 8388608.0f);
        unsigned p = ((b0 & 0xFFu) | ((b1 & 0xFFu) << 8) | ((b2 & 0xFFu) << 16) |
                      ((b3 & 0xFFu) << 24)) ^ 0x80808080u;
        *(unsigned*)&yt[((size_t)b << 20) + (size_t)(nt + nn) * 1024 + kt + ky * 4] = p;
    }
}

// ---- GEMM: 128x128, 4 waves, BK=64B, 4-deep pipeline, i8 MFMA ----
__global__ __launch_bounds__(256) void k_gemm(const unsigned char* __restrict__ xb,
                                              const unsigned char* __restrict__ yt,
                                              const float* __restrict__ rx,
                                              const float* __restrict__ cy,
                                              float* __restrict__ out) {
    __shared__ __align__(16) unsigned char As[4][128 * 64];
    __shared__ __align__(16) unsigned char Bs[4][128 * 64];

    int bid = blockIdx.x;
    int wg  = (bid & 7) * (NG * 64 / 8) + (bid >> 3);   // bijective XCD swizzle
    int g   = wg >> 6;
    int t   = wg & 63;
    int m0  = (t >> 3) * 128, n0 = (t & 7) * 128;
    int b   = g & 7;

    int tid = threadIdx.x, lane = tid & 63, w = tid >> 6;
    int wm = w >> 1, wn = w & 1;

    const unsigned char* Ab = xb + (size_t)g * 1048576 + (size_t)m0 * 1024;
    const unsigned char* Bb = yt + ((size_t)b << 20) + (size_t)n0 * 1024;

    // staging: LDS slot (row, c) holds global (row, c ^ ((row>>1)&3)); dest linear.
    int srow   = tid >> 2;                          // 0..63 (group0), +64 (group1)
    int schunk = (tid & 3) ^ ((srow >> 1) & 3);
    size_t off0 = (size_t)srow * 1024 + schunk * 16;
    size_t off1 = off0 + 64 * 1024;                 // key same for row+64
    int dst0 = (tid & ~63) * 16;
    int dst1 = (256 + (tid & ~63)) * 16;

#define STAGE(buf, kt) do {                                   \
    GLOAD16(Ab + off0 + (size_t)(kt) * 64, &As[buf][dst0]);   \
    GLOAD16(Ab + off1 + (size_t)(kt) * 64, &As[buf][dst1]);   \
    GLOAD16(Bb + off0 + (size_t)(kt) * 64, &Bs[buf][dst0]);   \
    GLOAD16(Bb + off1 + (size_t)(kt) * 64, &Bs[buf][dst1]);   \
} while (0)

    v16i acc[2][2];
#pragma unroll
    for (int i = 0; i < 2; ++i)
#pragma unroll
        for (int j = 0; j < 2; ++j)
#pragma unroll
            for (int q = 0; q < 16; ++q) acc[i][j][q] = 0;

    // fragment reads (swizzled): row = blk*32 + (lane&31); key=(row>>1)&3=(lane>>1)&3
    // logical chunk = kk*2 + hi  ->  lds chunk = logical ^ key
    int arow = lane & 31, hi = lane >> 5, key = (lane >> 1) & 3;
    int rA0 = (wm * 64 + arow) * 64, rA1 = rA0 + 32 * 64;
    int rB0 = (wn * 64 + arow) * 64, rB1 = rB0 + 32 * 64;
    int c0 = (hi ^ key) * 16;          // kk=0
    int c1 = ((2 + hi) ^ key) * 16;    // kk=1

#define COMPUTE(bi) do {                                                         \
    v4i a0k0 = *(const v4i*)&As[bi][rA0 + c0];                                   \
    v4i a1k0 = *(const v4i*)&As[bi][rA1 + c0];                                   \
    v4i b0k0 = *(const v4i*)&Bs[bi][rB0 + c0];                                   \
    v4i b1k0 = *(const v4i*)&Bs[bi][rB1 + c0];                                   \
    v4i a0k1 = *(const v4i*)&As[bi][rA0 + c1];                                   \
    v4i a1k1 = *(const v4i*)&As[bi][rA1 + c1];                                   \
    v4i b0k1 = *(const v4i*)&Bs[bi][rB0 + c1];                                   \
    v4i b1k1 = *(const v4i*)&Bs[bi][rB1 + c1];                                   \
    acc[0][0] = __builtin_amdgcn_mfma_i32_32x32x32_i8(a0k0, b0k0, acc[0][0], 0, 0, 0); \
    acc[0][1] = __builtin_amdgcn_mfma_i32_32x32x32_i8(a0k0, b1k0, acc[0][1], 0, 0, 0); \
    acc[1][0] = __builtin_amdgcn_mfma_i32_32x32x32_i8(a1k0, b0k0, acc[1][0], 0, 0, 0); \
    acc[1][1] = __builtin_amdgcn_mfma_i32_32x32x32_i8(a1k0, b1k0, acc[1][1], 0, 0, 0); \
    acc[0][0] = __builtin_amdgcn_mfma_i32_32x32x32_i8(a0k1, b0k1, acc[0][0], 0, 0, 0); \
    acc[0][1] = __builtin_amdgcn_mfma_i32_32x32x32_i8(a0k1, b1k1, acc[0][1], 0, 0, 0); \
    acc[1][0] = __builtin_amdgcn_mfma_i32_32x32x32_i8(a1k1, b0k1, acc[1][0], 0, 0, 0); \
    acc[1][1] = __builtin_amdgcn_mfma_i32_32x32x32_i8(a1k1, b1k1, acc[1][1], 0, 0, 0); \
} while (0)

    // prologue: 3 tiles in flight
    STAGE(0, 0);
    STAGE(1, 1);
    STAGE(2, 2);

    // main loop: counted vmcnt (12 outstanding -> drain oldest 4), ONE barrier/step
    for (int kt = 0; kt < 13; ++kt) {
        asm volatile("s_waitcnt vmcnt(8)" ::: "memory");
        __syncthreads();
        STAGE((kt + 3) & 3, kt + 3);
        COMPUTE(kt & 3);
    }
    // kt=13: outstanding 13,14,15 -> drain 13
    asm volatile("s_waitcnt vmcnt(8)" ::: "memory");
    __syncthreads();
    COMPUTE(1);
    // kt=14
    asm volatile("s_waitcnt vmcnt(4)" ::: "memory");
    __syncthreads();
    COMPUTE(2);
    // kt=15
    asm volatile("s_waitcnt vmcnt(0)" ::: "memory");
    __syncthreads();
    COMPUTE(3);
#undef COMPUTE
#undef STAGE

    // epilogue: out = 7.5e-4 * (S' - 32*Rx + 66*Cy - 10813440)
    // C/D layout: col = lane&31, row = (q&3) + 8*(q>>2) + 4*(lane>>5)
    const float* rxp = rx + g * 1024 + m0 + wm * 64;
    const float* cyp = cy + b * 1024 + n0 + wn * 64;
    float* og = out + (size_t)g * 1048576 + (size_t)(m0 + wm * 64) * 1024 + n0 + wn * 64;
    int col = lane & 31, r4 = hi * 4;
#pragma unroll
    for (int fi = 0; fi < 2; ++fi)
#pragma unroll
        for (int fj = 0; fj < 2; ++fj) {
            int cc = fj * 32 + col;
            float cv = cyp[cc];
            v16i v = acc[fi][fj];
#pragma unroll
            for (int q = 0; q < 16; ++q) {
                int rl = (q & 3) + 8 * (q >> 2) + r4;
                float rxv = rxp[fi * 32 + rl];
                og[(size_t)(fi * 32 + rl) * 1024 + cc] =
                    7.5e-4f * ((float)v[q] - 32.0f * rxv + 66.0f * cv - 10813440.0f);
            }
        }
}

// ---- emergency fallback ----
__global__ void k_naive(const float* __restrict__ x, const float* __restrict__ y,
                        float* __restrict__ out) {
    int g = blockIdx.z, b = g & 7;
    int tx = threadIdx.x, ty = threadIdx.y;
    int m = blockIdx.y * 16 + ty, n = blockIdx.x * 16 + tx;
    __shared__ float a[16][17], bs[16][17];
    float s = 0.f;
    for (int kt = 0; kt < 64; ++kt) {
        a[ty][tx]  = x[(size_t)g * 1048576 + (size_t)m * 1024 + kt * 16 + tx];
        bs[ty][tx] = y[(size_t)b * 1048576 + (size_t)(kt * 16 + ty) * 1024 + n];
        __syncthreads();
#pragma unroll
        for (int j = 0; j < 16; ++j)
            s += ((a[ty][j] + 66.0f) * 0.03f) * ((bs[j][tx] - 160.0f) * 0.025f);
        __syncthreads();
    }
    out[(size_t)g * 1048576 + (size_t)m * 1024 + n] = s;
}

extern "C" void kernel_launch(void* const* d_in, const int* in_sizes, int n_in,
                              void* d_out, int out_size, void* d_ws, size_t ws_size,
                              hipStream_t stream) {
    const float* x = (const float*)d_in[0];
    const float* y = (const float*)d_in[1];
    float* out = (float*)d_out;

    const size_t CY_OFF = 0;                         // 32 KB
    const size_t RX_OFF = 32768;                     // 224 KB
    const size_t YT_OFF = 262144;                    // 8 MB
    const size_t XB_OFF = 262144 + 8388608ull;       // 56 MB
    const size_t NEED   = XB_OFF + 58720256ull;

    if (ws_size >= NEED) {
        float* cy         = (float*)((char*)d_ws + CY_OFF);
        float* rx         = (float*)((char*)d_ws + RX_OFF);
        unsigned char* yt = (unsigned char*)((char*)d_ws + YT_OFF);
        unsigned char* xb = (unsigned char*)((char*)d_ws + XB_OFF);
        hipMemsetAsync(cy, 0, 32768, stream);
        k_prep_x<<<14336, 256, 0, stream>>>(x, xb, rx);
        k_prep_y<<<2048, 256, 0, stream>>>(y, yt, cy);
        k_gemm<<<NG * 64, 256, 0, stream>>>(xb, yt, rx, cy, out);
    } else {
        dim3 grid(64, 64, NG), blk(16, 16);
        k_naive<<<grid, blk, 0, stream>>>(x, y, out);
    }
}

// Round 5
// 214.649 us; speedup vs baseline: 1.0527x; 1.0527x over previous
//
#include <hip/hip_runtime.h>
#include <cstdint>

// out[s,b,m,n] = sum_k (x+66)*0.03 * (y-160)*0.025,  S=7 B=8 M=K=N=1024
// y' = y-128; x, y' are exact int8. i8 MFMA (int32-exact):
//   out = 7.5e-4 * ( S' - 32*Rx[m] + 66*Cy[n] - 10813440 ),  S' = sum x*y'
// GEMM: 128x128 tile, 4 waves, BK=64B, 4-deep multibuffer, counted vmcnt(8),
// RAW s_barrier (not __syncthreads -- hipcc drains vmcnt(0) before those!),
// XOR swizzle key=(row>>1)&3, setprio around MFMA cluster.

#define NG 56

typedef int v4i  __attribute__((ext_vector_type(4)));
typedef int v16i __attribute__((ext_vector_type(16)));

#define GLOAD16(g, l) __builtin_amdgcn_global_load_lds( \
    (const __attribute__((address_space(1))) void*)(g), \
    (__attribute__((address_space(3))) void*)(l), 16, 0, 0)

__device__ __forceinline__ unsigned pack4(float4 v, float& s) {
    s += (v.x + v.y) + (v.z + v.w);
    unsigned b0 = __float_as_uint(v.x + 8388736.0f);  // 2^23 + 128
    unsigned b1 = __float_as_uint(v.y + 8388736.0f);
    unsigned b2 = __float_as_uint(v.z + 8388736.0f);
    unsigned b3 = __float_as_uint(v.w + 8388736.0f);
    return ((b0 & 0xFFu) | ((b1 & 0xFFu) << 8) | ((b2 & 0xFFu) << 16) | ((b3 & 0xFFu) << 24))
           ^ 0x80808080u;
}

// ---- prepass 1: x -> i8 + row sums ----
__global__ __launch_bounds__(256) void k_prep_x(const float* __restrict__ x,
                                                unsigned char* __restrict__ xb,
                                                float* __restrict__ rx) {
    int row  = blockIdx.x * 4 + (threadIdx.x >> 6);
    int lane = threadIdx.x & 63;
    const float* src = x + (size_t)row * 1024;
    float s = 0.f;
#pragma unroll
    for (int it = 0; it < 4; ++it) {
        float4 v = *(const float4*)(src + it * 256 + lane * 4);
        unsigned p = pack4(v, s);
        *(unsigned*)&xb[(size_t)row * 1024 + it * 256 + lane * 4] = p;
    }
#pragma unroll
    for (int off = 32; off > 0; off >>= 1) s += __shfl_down(s, off);
    if (lane == 0) rx[row] = s;
}

// ---- prepass 2: y [b][k][n] -> yt [b][n][k] i8 (= y-128), + col sums Cy ----
__global__ __launch_bounds__(256) void k_prep_y(const float* __restrict__ y,
                                                unsigned char* __restrict__ yt,
                                                float* __restrict__ cy) {
    __shared__ float tile[64][65];
    __shared__ float csum[4][64];
    int b  = blockIdx.x >> 8;
    int t  = blockIdx.x & 255;
    int kt = (t >> 4) * 64, nt = (t & 15) * 64;
    int tx = threadIdx.x & 63;
    int ty = threadIdx.x >> 6;
    const float* src = y + ((size_t)b << 20) + (size_t)kt * 1024 + nt;
    float part = 0.f;
#pragma unroll
    for (int r = 0; r < 16; ++r) {
        int kk = r * 4 + ty;
        float v = src[(size_t)kk * 1024 + tx];
        tile[kk][tx] = v;
        part += v;
    }
    csum[ty][tx] = part;
    __syncthreads();
    if (threadIdx.x < 64) {
        float s = csum[0][tx] + csum[1][tx] + csum[2][tx] + csum[3][tx];
        atomicAdd(&cy[b * 1024 + nt + tx], s);
    }
    int ky = threadIdx.x & 15;
    int ny = threadIdx.x >> 4;
#pragma unroll
    for (int r = 0; r < 4; ++r) {
        int nn = r * 16 + ny;
        unsigned b0 = __float_as_uint(tile[ky * 4 + 0][nn] + 8388608.0f);
        unsigned b1 = __float_as_uint(tile[ky * 4 + 1][nn] + 8388608.0f);
        unsigned b2 = __float_as_uint(tile[ky * 4 + 2][nn] + 8388608.0f);
        unsigned b3 = __float_as_uint(tile[ky * 4 + 3][nn] + 8388608.0f);
        unsigned p = ((b0 & 0xFFu) | ((b1 & 0xFFu) << 8) | ((b2 & 0xFFu) << 16) |
                      ((b3 & 0xFFu) << 24)) ^ 0x80808080u;
        *(unsigned*)&yt[((size_t)b << 20) + (size_t)(nt + nn) * 1024 + kt + ky * 4] = p;
    }
}

// ---- GEMM: 128x128, 4 waves, BK=64B, 4-deep pipeline, i8 MFMA ----
__global__ __launch_bounds__(256) void k_gemm(const unsigned char* __restrict__ xb,
                                              const unsigned char* __restrict__ yt,
                                              const float* __restrict__ rx,
                                              const float* __restrict__ cy,
                                              float* __restrict__ out) {
    __shared__ __align__(16) unsigned char As[4][128 * 64];
    __shared__ __align__(16) unsigned char Bs[4][128 * 64];

    int bid = blockIdx.x;
    int wg  = (bid & 7) * (NG * 64 / 8) + (bid >> 3);   // bijective XCD swizzle
    int g   = wg >> 6;
    int t   = wg & 63;
    int m0  = (t >> 3) * 128, n0 = (t & 7) * 128;
    int b   = g & 7;

    int tid = threadIdx.x, lane = tid & 63, w = tid >> 6;
    int wm = w >> 1, wn = w & 1;

    const unsigned char* Ab = xb + (size_t)g * 1048576 + (size_t)m0 * 1024;
    const unsigned char* Bb = yt + ((size_t)b << 20) + (size_t)n0 * 1024;

    // staging: LDS slot (row, c) holds global (row, c ^ ((row>>1)&3)); dest linear.
    int srow   = tid >> 2;
    int schunk = (tid & 3) ^ ((srow >> 1) & 3);
    size_t off0 = (size_t)srow * 1024 + schunk * 16;
    size_t off1 = off0 + 64 * 1024;
    int dst0 = (tid & ~63) * 16;
    int dst1 = (256 + (tid & ~63)) * 16;

#define STAGE(buf, kt) do {                                   \
    GLOAD16(Ab + off0 + (size_t)(kt) * 64, &As[buf][dst0]);   \
    GLOAD16(Ab + off1 + (size_t)(kt) * 64, &As[buf][dst1]);   \
    GLOAD16(Bb + off0 + (size_t)(kt) * 64, &Bs[buf][dst0]);   \
    GLOAD16(Bb + off1 + (size_t)(kt) * 64, &Bs[buf][dst1]);   \
} while (0)

    v16i acc[2][2];
#pragma unroll
    for (int i = 0; i < 2; ++i)
#pragma unroll
        for (int j = 0; j < 2; ++j)
#pragma unroll
            for (int q = 0; q < 16; ++q) acc[i][j][q] = 0;

    // fragment reads (swizzled): row = blk*32 + (lane&31); key=(lane>>1)&3
    int arow = lane & 31, hi = lane >> 5, key = (lane >> 1) & 3;
    int rA0 = (wm * 64 + arow) * 64, rA1 = rA0 + 32 * 64;
    int rB0 = (wn * 64 + arow) * 64, rB1 = rB0 + 32 * 64;
    int c0 = (hi ^ key) * 16;          // kk=0
    int c1 = ((2 + hi) ^ key) * 16;    // kk=1

#define COMPUTE(bi) do {                                                         \
    v4i a0k0 = *(const v4i*)&As[bi][rA0 + c0];                                   \
    v4i a1k0 = *(const v4i*)&As[bi][rA1 + c0];                                   \
    v4i b0k0 = *(const v4i*)&Bs[bi][rB0 + c0];                                   \
    v4i b1k0 = *(const v4i*)&Bs[bi][rB1 + c0];                                   \
    v4i a0k1 = *(const v4i*)&As[bi][rA0 + c1];                                   \
    v4i a1k1 = *(const v4i*)&As[bi][rA1 + c1];                                   \
    v4i b0k1 = *(const v4i*)&Bs[bi][rB0 + c1];                                   \
    v4i b1k1 = *(const v4i*)&Bs[bi][rB1 + c1];                                   \
    __builtin_amdgcn_s_setprio(1);                                               \
    acc[0][0] = __builtin_amdgcn_mfma_i32_32x32x32_i8(a0k0, b0k0, acc[0][0], 0, 0, 0); \
    acc[0][1] = __builtin_amdgcn_mfma_i32_32x32x32_i8(a0k0, b1k0, acc[0][1], 0, 0, 0); \
    acc[1][0] = __builtin_amdgcn_mfma_i32_32x32x32_i8(a1k0, b0k0, acc[1][0], 0, 0, 0); \
    acc[1][1] = __builtin_amdgcn_mfma_i32_32x32x32_i8(a1k0, b1k0, acc[1][1], 0, 0, 0); \
    acc[0][0] = __builtin_amdgcn_mfma_i32_32x32x32_i8(a0k1, b0k1, acc[0][0], 0, 0, 0); \
    acc[0][1] = __builtin_amdgcn_mfma_i32_32x32x32_i8(a0k1, b1k1, acc[0][1], 0, 0, 0); \
    acc[1][0] = __builtin_amdgcn_mfma_i32_32x32x32_i8(a1k1, b0k1, acc[1][0], 0, 0, 0); \
    acc[1][1] = __builtin_amdgcn_mfma_i32_32x32x32_i8(a1k1, b1k1, acc[1][1], 0, 0, 0); \
    __builtin_amdgcn_s_setprio(0);                                               \
} while (0)

// counted-vmcnt barrier: RAW s_barrier; do NOT use __syncthreads (it drains vmcnt(0))
#define PIPE_BARRIER(N) do {                                  \
    asm volatile("s_waitcnt vmcnt(" #N ")" ::: "memory");     \
    __builtin_amdgcn_s_barrier();                             \
    __builtin_amdgcn_sched_barrier(0);                        \
} while (0)

    // prologue: 3 tiles (12 loads) in flight
    STAGE(0, 0);
    STAGE(1, 1);
    STAGE(2, 2);

    for (int kt = 0; kt < 13; ++kt) {
        PIPE_BARRIER(8);                 // oldest tile (kt) landed, 8 still flying
        STAGE((kt + 3) & 3, kt + 3);     // refill to 12 outstanding
        COMPUTE(kt & 3);
    }
    PIPE_BARRIER(8);   COMPUTE(1);       // kt=13
    PIPE_BARRIER(4);   COMPUTE(2);       // kt=14
    PIPE_BARRIER(0);   COMPUTE(3);       // kt=15
#undef COMPUTE
#undef STAGE
#undef PIPE_BARRIER

    // epilogue: out = 7.5e-4 * (S' - 32*Rx + 66*Cy - 10813440)
    // C/D layout: col = lane&31, row = (q&3) + 8*(q>>2) + 4*(lane>>5)
    const float* rxp = rx + g * 1024 + m0 + wm * 64;
    const float* cyp = cy + b * 1024 + n0 + wn * 64;
    float* og = out + (size_t)g * 1048576 + (size_t)(m0 + wm * 64) * 1024 + n0 + wn * 64;
    int col = lane & 31, r4 = hi * 4;
#pragma unroll
    for (int fi = 0; fi < 2; ++fi)
#pragma unroll
        for (int fj = 0; fj < 2; ++fj) {
            int cc = fj * 32 + col;
            float cv = cyp[cc];
            v16i v = acc[fi][fj];
#pragma unroll
            for (int q = 0; q < 16; ++q) {
                int rl = (q & 3) + 8 * (q >> 2) + r4;
                float rxv = rxp[fi * 32 + rl];
                og[(size_t)(fi * 32 + rl) * 1024 + cc] =
                    7.5e-4f * ((float)v[q] - 32.0f * rxv + 66.0f * cv - 10813440.0f);
            }
        }
}

// ---- emergency fallback ----
__global__ void k_naive(const float* __restrict__ x, const float* __restrict__ y,
                        float* __restrict__ out) {
    int g = blockIdx.z, b = g & 7;
    int tx = threadIdx.x, ty = threadIdx.y;
    int m = blockIdx.y * 16 + ty, n = blockIdx.x * 16 + tx;
    __shared__ float a[16][17], bs[16][17];
    float s = 0.f;
    for (int kt = 0; kt < 64; ++kt) {
        a[ty][tx]  = x[(size_t)g * 1048576 + (size_t)m * 1024 + kt * 16 + tx];
        bs[ty][tx] = y[(size_t)b * 1048576 + (size_t)(kt * 16 + ty) * 1024 + n];
        __syncthreads();
#pragma unroll
        for (int j = 0; j < 16; ++j)
            s += ((a[ty][j] + 66.0f) * 0.03f) * ((bs[j][tx] - 160.0f) * 0.025f);
        __syncthreads();
    }
    out[(size_t)g * 1048576 + (size_t)m * 1024 + n] = s;
}

extern "C" void kernel_launch(void* const* d_in, const int* in_sizes, int n_in,
                              void* d_out, int out_size, void* d_ws, size_t ws_size,
                              hipStream_t stream) {
    const float* x = (const float*)d_in[0];
    const float* y = (const float*)d_in[1];
    float* out = (float*)d_out;

    const size_t CY_OFF = 0;                         // 32 KB
    const size_t RX_OFF = 32768;                     // 224 KB
    const size_t YT_OFF = 262144;                    // 8 MB
    const size_t XB_OFF = 262144 + 8388608ull;       // 56 MB
    const size_t NEED   = XB_OFF + 58720256ull;

    if (ws_size >= NEED) {
        float* cy         = (float*)((char*)d_ws + CY_OFF);
        float* rx         = (float*)((char*)d_ws + RX_OFF);
        unsigned char* yt = (unsigned char*)((char*)d_ws + YT_OFF);
        unsigned char* xb = (unsigned char*)((char*)d_ws + XB_OFF);
        hipMemsetAsync(cy, 0, 32768, stream);
        k_prep_x<<<14336, 256, 0, stream>>>(x, xb, rx);
        k_prep_y<<<2048, 256, 0, stream>>>(y, yt, cy);
        k_gemm<<<NG * 64, 256, 0, stream>>>(xb, yt, rx, cy, out);
    } else {
        dim3 grid(64, 64, NG), blk(16, 16);
        k_naive<<<grid, blk, 0, stream>>>(x, y, out);
    }
}

// Round 6
// 195.808 us; speedup vs baseline: 1.1539x; 1.0962x over previous
//
#include <hip/hip_runtime.h>
#include <cstdint>

// out[s,b,m,n] = sum_k (x+66)*0.03 * (y-160)*0.025,  S=7 B=8 M=K=N=1024
// y' = y-128; x, y' exact int8. i8 MFMA (int32-exact):
//   out = 7.5e-4 * ( S' - 32*Rx[m] + 66*Cy[n] - 10813440 ),  S' = sum x*y'
// GEMM: 256x256 tile, 8 waves (2Mx4N), BK=64B, 4-deep LDS ring (128KB),
// counted vmcnt(8) at tile start, 2 phases/tile {6 ds_read || 2 gload -> raw
// s_barrier -> setprio(1) 8xMFMA}, XOR swizzle key=(row>>1)&3.

#define NG 56

typedef int v4i  __attribute__((ext_vector_type(4)));
typedef int v16i __attribute__((ext_vector_type(16)));

#define GLOAD16(g, l) __builtin_amdgcn_global_load_lds( \
    (const __attribute__((address_space(1))) void*)(g), \
    (__attribute__((address_space(3))) void*)(l), 16, 0, 0)

#define MFMA_I8(a, b, c) __builtin_amdgcn_mfma_i32_32x32x32_i8(a, b, c, 0, 0, 0)

__device__ __forceinline__ unsigned pack4(float4 v, float& s) {
    s += (v.x + v.y) + (v.z + v.w);
    unsigned b0 = __float_as_uint(v.x + 8388736.0f);  // 2^23 + 128
    unsigned b1 = __float_as_uint(v.y + 8388736.0f);
    unsigned b2 = __float_as_uint(v.z + 8388736.0f);
    unsigned b3 = __float_as_uint(v.w + 8388736.0f);
    return ((b0 & 0xFFu) | ((b1 & 0xFFu) << 8) | ((b2 & 0xFFu) << 16) | ((b3 & 0xFFu) << 24))
           ^ 0x80808080u;
}

// ---- prepass 1: x -> i8 + row sums ----
__global__ __launch_bounds__(256) void k_prep_x(const float* __restrict__ x,
                                                unsigned char* __restrict__ xb,
                                                float* __restrict__ rx) {
    int row  = blockIdx.x * 4 + (threadIdx.x >> 6);
    int lane = threadIdx.x & 63;
    const float* src = x + (size_t)row * 1024;
    float s = 0.f;
#pragma unroll
    for (int it = 0; it < 4; ++it) {
        float4 v = *(const float4*)(src + it * 256 + lane * 4);
        unsigned p = pack4(v, s);
        *(unsigned*)&xb[(size_t)row * 1024 + it * 256 + lane * 4] = p;
    }
#pragma unroll
    for (int off = 32; off > 0; off >>= 1) s += __shfl_down(s, off);
    if (lane == 0) rx[row] = s;
}

// ---- prepass 2: y [b][k][n] -> yt [b][n][k] i8 (= y-128), + col sums Cy ----
__global__ __launch_bounds__(256) void k_prep_y(const float* __restrict__ y,
                                                unsigned char* __restrict__ yt,
                                                float* __restrict__ cy) {
    __shared__ float tile[64][65];
    __shared__ float csum[4][64];
    int b  = blockIdx.x >> 8;
    int t  = blockIdx.x & 255;
    int kt = (t >> 4) * 64, nt = (t & 15) * 64;
    int tx = threadIdx.x & 63;
    int ty = threadIdx.x >> 6;
    const float* src = y + ((size_t)b << 20) + (size_t)kt * 1024 + nt;
    float part = 0.f;
#pragma unroll
    for (int r = 0; r < 16; ++r) {
        int kk = r * 4 + ty;
        float v = src[(size_t)kk * 1024 + tx];
        tile[kk][tx] = v;
        part += v;
    }
    csum[ty][tx] = part;
    __syncthreads();
    if (threadIdx.x < 64) {
        float s = csum[0][tx] + csum[1][tx] + csum[2][tx] + csum[3][tx];
        atomicAdd(&cy[b * 1024 + nt + tx], s);
    }
    int ky = threadIdx.x & 15;
    int ny = threadIdx.x >> 4;
#pragma unroll
    for (int r = 0; r < 4; ++r) {
        int nn = r * 16 + ny;
        unsigned b0 = __float_as_uint(tile[ky * 4 + 0][nn] + 8388608.0f);
        unsigned b1 = __float_as_uint(tile[ky * 4 + 1][nn] + 8388608.0f);
        unsigned b2 = __float_as_uint(tile[ky * 4 + 2][nn] + 8388608.0f);
        unsigned b3 = __float_as_uint(tile[ky * 4 + 3][nn] + 8388608.0f);
        unsigned p = ((b0 & 0xFFu) | ((b1 & 0xFFu) << 8) | ((b2 & 0xFFu) << 16) |
                      ((b3 & 0xFFu) << 24)) ^ 0x80808080u;
        *(unsigned*)&yt[((size_t)b << 20) + (size_t)(nt + nn) * 1024 + kt + ky * 4] = p;
    }
}

// ---- GEMM: 256x256, 8 waves, BK=64B, 4-ring, phase-split i8 MFMA ----
__global__ __launch_bounds__(512) void k_gemm(const unsigned char* __restrict__ xb,
                                              const unsigned char* __restrict__ yt,
                                              const float* __restrict__ rx,
                                              const float* __restrict__ cy,
                                              float* __restrict__ out) {
    __shared__ __align__(16) unsigned char As[4][256 * 64];
    __shared__ __align__(16) unsigned char Bs[4][256 * 64];

    int bid = blockIdx.x;                         // 896 = 8 * 112, bijective
    int wg  = (bid & 7) * 112 + (bid >> 3);
    int g   = wg >> 4;
    int t   = wg & 15;
    int m0  = (t >> 2) * 256, n0 = (t & 3) * 256;
    int b   = g & 7;

    int tid = threadIdx.x, lane = tid & 63, w = tid >> 6;
    int wm = w >> 2, wn = w & 3;                  // 2M x 4N wave grid

    const unsigned char* Ab = xb + (size_t)g * 1048576 + (size_t)m0 * 1024;
    const unsigned char* Bb = yt + ((size_t)b << 20) + (size_t)n0 * 1024;

    // staging: chunk_id cid -> LDS row cid>>2, phys chunk cid&3 (16B units);
    // LDS (row,c) holds global (row, c ^ ((row>>1)&3)).  j=0: rows 0..127, j=1: 128..255.
    int cid0 = tid, cid1 = 512 + tid;
    size_t soff0 = (size_t)(cid0 >> 2) * 1024 + (size_t)(((cid0 & 3) ^ ((cid0 >> 3) & 3)) * 16);
    size_t soff1 = (size_t)(cid1 >> 2) * 1024 + (size_t)(((cid1 & 3) ^ ((cid1 >> 3) & 3)) * 16);
    int dst0 = (tid & ~63) * 16;
    int dst1 = (512 + (tid & ~63)) * 16;

    v16i acc[4][2];
#pragma unroll
    for (int i = 0; i < 4; ++i)
#pragma unroll
        for (int j = 0; j < 2; ++j)
#pragma unroll
            for (int q = 0; q < 16; ++q) acc[i][j][q] = 0;

    // fragment reads (swizzled): row = base + (lane&31); key = (lane>>1)&3
    int arow = lane & 31, hi = lane >> 5, key = (lane >> 1) & 3;
    int rA0 = (wm * 128 +  0 + arow) * 64;
    int rA1 = (wm * 128 + 32 + arow) * 64;
    int rA2 = (wm * 128 + 64 + arow) * 64;
    int rA3 = (wm * 128 + 96 + arow) * 64;
    int rB0 = (wn * 64 +  0 + arow) * 64;
    int rB1 = (wn * 64 + 32 + arow) * 64;
    int ck0 = (hi ^ key) * 16;          // kk=0
    int ck1 = ((2 + hi) ^ key) * 16;    // kk=1

#define STAGE_J0(buf, kt) do {                                      \
    GLOAD16(Ab + (size_t)(kt) * 64 + soff0, &As[buf][dst0]);        \
    GLOAD16(Bb + (size_t)(kt) * 64 + soff0, &Bs[buf][dst0]);        \
} while (0)
#define STAGE_J1(buf, kt) do {                                      \
    GLOAD16(Ab + (size_t)(kt) * 64 + soff1, &As[buf][dst1]);        \
    GLOAD16(Bb + (size_t)(kt) * 64 + soff1, &Bs[buf][dst1]);        \
} while (0)

#define BARRIER_FENCE() do {                   \
    __builtin_amdgcn_s_barrier();              \
    asm volatile("" ::: "memory");             \
    __builtin_amdgcn_sched_barrier(0);         \
} while (0)

#define MFMA8(A0, A1, A2, A3, B0, B1) do {     \
    __builtin_amdgcn_s_setprio(1);             \
    acc[0][0] = MFMA_I8(A0, B0, acc[0][0]);    \
    acc[0][1] = MFMA_I8(A0, B1, acc[0][1]);    \
    acc[1][0] = MFMA_I8(A1, B0, acc[1][0]);    \
    acc[1][1] = MFMA_I8(A1, B1, acc[1][1]);    \
    acc[2][0] = MFMA_I8(A2, B0, acc[2][0]);    \
    acc[2][1] = MFMA_I8(A2, B1, acc[2][1]);    \
    acc[3][0] = MFMA_I8(A3, B0, acc[3][0]);    \
    acc[3][1] = MFMA_I8(A3, B1, acc[3][1]);    \
    __builtin_amdgcn_s_setprio(0);             \
} while (0)

    // prologue: 3 tiles (12 loads/thread) in flight
    STAGE_J0(0, 0); STAGE_J1(0, 0);
    STAGE_J0(1, 1); STAGE_J1(1, 1);
    STAGE_J0(2, 2); STAGE_J1(2, 2);

    for (int kt = 0; kt < 13; ++kt) {
        int bi = kt & 3, pb = (kt + 3) & 3;
        asm volatile("s_waitcnt vmcnt(8)" ::: "memory");   // tile kt landed
        BARRIER_FENCE();
        // phase 0 (kk=0): reads + prefetch j0, then MFMA
        {
            v4i a0 = *(const v4i*)&As[bi][rA0 + ck0];
            v4i a1 = *(const v4i*)&As[bi][rA1 + ck0];
            v4i a2 = *(const v4i*)&As[bi][rA2 + ck0];
            v4i a3 = *(const v4i*)&As[bi][rA3 + ck0];
            v4i b0 = *(const v4i*)&Bs[bi][rB0 + ck0];
            v4i b1 = *(const v4i*)&Bs[bi][rB1 + ck0];
            STAGE_J0(pb, kt + 3);
            BARRIER_FENCE();
            MFMA8(a0, a1, a2, a3, b0, b1);
        }
        // phase 1 (kk=1)
        {
            v4i a0 = *(const v4i*)&As[bi][rA0 + ck1];
            v4i a1 = *(const v4i*)&As[bi][rA1 + ck1];
            v4i a2 = *(const v4i*)&As[bi][rA2 + ck1];
            v4i a3 = *(const v4i*)&As[bi][rA3 + ck1];
            v4i b0 = *(const v4i*)&Bs[bi][rB0 + ck1];
            v4i b1 = *(const v4i*)&Bs[bi][rB1 + ck1];
            STAGE_J1(pb, kt + 3);
            BARRIER_FENCE();
            MFMA8(a0, a1, a2, a3, b0, b1);
        }
    }

#define TAIL_TILE(bi, VM) do {                                       \
    asm volatile("s_waitcnt vmcnt(" #VM ")" ::: "memory");           \
    BARRIER_FENCE();                                                 \
    {                                                                \
        v4i a0 = *(const v4i*)&As[bi][rA0 + ck0];                    \
        v4i a1 = *(const v4i*)&As[bi][rA1 + ck0];                    \
        v4i a2 = *(const v4i*)&As[bi][rA2 + ck0];                    \
        v4i a3 = *(const v4i*)&As[bi][rA3 + ck0];                    \
        v4i b0 = *(const v4i*)&Bs[bi][rB0 + ck0];                    \
        v4i b1 = *(const v4i*)&Bs[bi][rB1 + ck0];                    \
        BARRIER_FENCE();                                             \
        MFMA8(a0, a1, a2, a3, b0, b1);                               \
    }                                                                \
    {                                                                \
        v4i a0 = *(const v4i*)&As[bi][rA0 + ck1];                    \
        v4i a1 = *(const v4i*)&As[bi][rA1 + ck1];                    \
        v4i a2 = *(const v4i*)&As[bi][rA2 + ck1];                    \
        v4i a3 = *(const v4i*)&As[bi][rA3 + ck1];                    \
        v4i b0 = *(const v4i*)&Bs[bi][rB0 + ck1];                    \
        v4i b1 = *(const v4i*)&Bs[bi][rB1 + ck1];                    \
        BARRIER_FENCE();                                             \
        MFMA8(a0, a1, a2, a3, b0, b1);                               \
    }                                                                \
} while (0)

    TAIL_TILE(1, 8);   // kt=13: tiles 13,14,15 in flight (12) -> drain to 8
    TAIL_TILE(2, 4);   // kt=14
    TAIL_TILE(3, 0);   // kt=15
#undef TAIL_TILE
#undef MFMA8
#undef BARRIER_FENCE
#undef STAGE_J0
#undef STAGE_J1

    // epilogue: out = 7.5e-4 * (S' - 32*Rx + 66*Cy - 10813440)
    // C/D layout: col = lane&31, row = (q&3) + 8*(q>>2) + 4*(lane>>5)
    const float* rxp = rx + g * 1024 + m0 + wm * 128;
    const float* cyp = cy + b * 1024 + n0 + wn * 64;
    float* og = out + (size_t)g * 1048576 + (size_t)(m0 + wm * 128) * 1024 + n0 + wn * 64;
    int col = lane & 31, r4 = hi * 4;
#pragma unroll
    for (int fi = 0; fi < 4; ++fi)
#pragma unroll
        for (int fj = 0; fj < 2; ++fj) {
            int cc = fj * 32 + col;
            float cv = cyp[cc];
            v16i v = acc[fi][fj];
#pragma unroll
            for (int q = 0; q < 16; ++q) {
                int rl = (q & 3) + 8 * (q >> 2) + r4;
                float rxv = rxp[fi * 32 + rl];
                og[(size_t)(fi * 32 + rl) * 1024 + cc] =
                    7.5e-4f * ((float)v[q] - 32.0f * rxv + 66.0f * cv - 10813440.0f);
            }
        }
}

// ---- emergency fallback ----
__global__ void k_naive(const float* __restrict__ x, const float* __restrict__ y,
                        float* __restrict__ out) {
    int g = blockIdx.z, b = g & 7;
    int tx = threadIdx.x, ty = threadIdx.y;
    int m = blockIdx.y * 16 + ty, n = blockIdx.x * 16 + tx;
    __shared__ float a[16][17], bs[16][17];
    float s = 0.f;
    for (int kt = 0; kt < 64; ++kt) {
        a[ty][tx]  = x[(size_t)g * 1048576 + (size_t)m * 1024 + kt * 16 + tx];
        bs[ty][tx] = y[(size_t)b * 1048576 + (size_t)(kt * 16 + ty) * 1024 + n];
        __syncthreads();
#pragma unroll
        for (int j = 0; j < 16; ++j)
            s += ((a[ty][j] + 66.0f) * 0.03f) * ((bs[j][tx] - 160.0f) * 0.025f);
        __syncthreads();
    }
    out[(size_t)g * 1048576 + (size_t)m * 1024 + n] = s;
}

extern "C" void kernel_launch(void* const* d_in, const int* in_sizes, int n_in,
                              void* d_out, int out_size, void* d_ws, size_t ws_size,
                              hipStream_t stream) {
    const float* x = (const float*)d_in[0];
    const float* y = (const float*)d_in[1];
    float* out = (float*)d_out;

    const size_t CY_OFF = 0;                         // 32 KB
    const size_t RX_OFF = 32768;                     // 224 KB
    const size_t YT_OFF = 262144;                    // 8 MB
    const size_t XB_OFF = 262144 + 8388608ull;       // 56 MB
    const size_t NEED   = XB_OFF + 58720256ull;

    if (ws_size >= NEED) {
        float* cy         = (float*)((char*)d_ws + CY_OFF);
        float* rx         = (float*)((char*)d_ws + RX_OFF);
        unsigned char* yt = (unsigned char*)((char*)d_ws + YT_OFF);
        unsigned char* xb = (unsigned char*)((char*)d_ws + XB_OFF);
        hipMemsetAsync(cy, 0, 32768, stream);
        k_prep_x<<<14336, 256, 0, stream>>>(x, xb, rx);
        k_prep_y<<<2048, 256, 0, stream>>>(y, yt, cy);
        k_gemm<<<NG * 16, 512, 0, stream>>>(xb, yt, rx, cy, out);
    } else {
        dim3 grid(64, 64, NG), blk(16, 16);
        k_naive<<<grid, blk, 0, stream>>>(x, y, out);
    }
}

// Round 7
// 195.250 us; speedup vs baseline: 1.1572x; 1.0029x over previous
//
#include <hip/hip_runtime.h>
#include <cstdint>

// out[s,b,m,n] = sum_k (x+66)*0.03 * (y-160)*0.025,  S=7 B=8 M=K=N=1024
// y' = y-128; x, y' exact int8. i8 MFMA (int32-exact):
//   out = 7.5e-4 * ( S' - 32*Rx[m] + 66*Cy[n] - 10813440 ),  S' = sum x*y'
// GEMM: 128x128 tile, 4 waves, BK=64B, 3-buffer LDS ring (48KB -> 3 blocks/CU),
// prefetch depth 2, counted vmcnt(4), raw s_barrier, and INLINE-ASM ds_read_b128
// so the compiler cannot alias fragment reads against global_load_lds writes
// (which otherwise makes it insert vmcnt(0) drains that defeat the pipeline).

#define NG 56

typedef int v4i  __attribute__((ext_vector_type(4)));
typedef int v16i __attribute__((ext_vector_type(16)));

#define GLOAD16(g, l) __builtin_amdgcn_global_load_lds( \
    (const __attribute__((address_space(1))) void*)(g), \
    (__attribute__((address_space(3))) void*)(l), 16, 0, 0)

#define MFMA_I8(a, b, c) __builtin_amdgcn_mfma_i32_32x32x32_i8(a, b, c, 0, 0, 0)

typedef __attribute__((address_space(3))) const unsigned char* lds_cptr;

__device__ __forceinline__ v4i lds_read16(lds_cptr p) {
    v4i d;
    asm volatile("ds_read_b128 %0, %1" : "=v"(d) : "v"(p));
    return d;
}

__device__ __forceinline__ unsigned pack4(float4 v, float& s) {
    s += (v.x + v.y) + (v.z + v.w);
    unsigned b0 = __float_as_uint(v.x + 8388736.0f);  // 2^23 + 128
    unsigned b1 = __float_as_uint(v.y + 8388736.0f);
    unsigned b2 = __float_as_uint(v.z + 8388736.0f);
    unsigned b3 = __float_as_uint(v.w + 8388736.0f);
    return ((b0 & 0xFFu) | ((b1 & 0xFFu) << 8) | ((b2 & 0xFFu) << 16) | ((b3 & 0xFFu) << 24))
           ^ 0x80808080u;
}

// ---- prepass 1: x -> i8 + row sums ----
__global__ __launch_bounds__(256) void k_prep_x(const float* __restrict__ x,
                                                unsigned char* __restrict__ xb,
                                                float* __restrict__ rx) {
    int row  = blockIdx.x * 4 + (threadIdx.x >> 6);
    int lane = threadIdx.x & 63;
    const float* src = x + (size_t)row * 1024;
    float s = 0.f;
#pragma unroll
    for (int it = 0; it < 4; ++it) {
        float4 v = *(const float4*)(src + it * 256 + lane * 4);
        unsigned p = pack4(v, s);
        *(unsigned*)&xb[(size_t)row * 1024 + it * 256 + lane * 4] = p;
    }
#pragma unroll
    for (int off = 32; off > 0; off >>= 1) s += __shfl_down(s, off);
    if (lane == 0) rx[row] = s;
}

// ---- prepass 2: y [b][k][n] -> yt [b][n][k] i8 (= y-128), + col sums Cy ----
__global__ __launch_bounds__(256) void k_prep_y(const float* __restrict__ y,
                                                unsigned char* __restrict__ yt,
                                                float* __restrict__ cy) {
    __shared__ float tile[64][65];
    __shared__ float csum[4][64];
    int b  = blockIdx.x >> 8;
    int t  = blockIdx.x & 255;
    int kt = (t >> 4) * 64, nt = (t & 15) * 64;
    int tx = threadIdx.x & 63;
    int ty = threadIdx.x >> 6;
    const float* src = y + ((size_t)b << 20) + (size_t)kt * 1024 + nt;
    float part = 0.f;
#pragma unroll
    for (int r = 0; r < 16; ++r) {
        int kk = r * 4 + ty;
        float v = src[(size_t)kk * 1024 + tx];
        tile[kk][tx] = v;
        part += v;
    }
    csum[ty][tx] = part;
    __syncthreads();
    if (threadIdx.x < 64) {
        float s = csum[0][tx] + csum[1][tx] + csum[2][tx] + csum[3][tx];
        atomicAdd(&cy[b * 1024 + nt + tx], s);
    }
    int ky = threadIdx.x & 15;
    int ny = threadIdx.x >> 4;
#pragma unroll
    for (int r = 0; r < 4; ++r) {
        int nn = r * 16 + ny;
        unsigned b0 = __float_as_uint(tile[ky * 4 + 0][nn] + 8388608.0f);
        unsigned b1 = __float_as_uint(tile[ky * 4 + 1][nn] + 8388608.0f);
        unsigned b2 = __float_as_uint(tile[ky * 4 + 2][nn] + 8388608.0f);
        unsigned b3 = __float_as_uint(tile[ky * 4 + 3][nn] + 8388608.0f);
        unsigned p = ((b0 & 0xFFu) | ((b1 & 0xFFu) << 8) | ((b2 & 0xFFu) << 16) |
                      ((b3 & 0xFFu) << 24)) ^ 0x80808080u;
        *(unsigned*)&yt[((size_t)b << 20) + (size_t)(nt + nn) * 1024 + kt + ky * 4] = p;
    }
}

// ---- GEMM: 128x128, 4 waves, BK=64B, 3-ring, asm ds_read, i8 MFMA ----
__global__ __launch_bounds__(256, 3) void k_gemm(const unsigned char* __restrict__ xb,
                                                 const unsigned char* __restrict__ yt,
                                                 const float* __restrict__ rx,
                                                 const float* __restrict__ cy,
                                                 float* __restrict__ out) {
    __shared__ __align__(16) unsigned char As[3][128 * 64];
    __shared__ __align__(16) unsigned char Bs[3][128 * 64];

    int bid = blockIdx.x;
    int wg  = (bid & 7) * (NG * 64 / 8) + (bid >> 3);   // bijective XCD swizzle
    int g   = wg >> 6;
    int t   = wg & 63;
    int m0  = (t >> 3) * 128, n0 = (t & 7) * 128;
    int b   = g & 7;

    int tid = threadIdx.x, lane = tid & 63, w = tid >> 6;
    int wm = w >> 1, wn = w & 1;

    const unsigned char* Ab = xb + (size_t)g * 1048576 + (size_t)m0 * 1024;
    const unsigned char* Bb = yt + ((size_t)b << 20) + (size_t)n0 * 1024;

    // staging: LDS slot (row, c) holds global (row, c ^ ((row>>1)&3)); dest linear.
    int srow   = tid >> 2;
    int schunk = (tid & 3) ^ ((srow >> 1) & 3);
    size_t off0 = (size_t)srow * 1024 + schunk * 16;
    size_t off1 = off0 + 64 * 1024;
    int dst0 = (tid & ~63) * 16;
    int dst1 = (256 + (tid & ~63)) * 16;

#define STAGE(buf, kt) do {                                   \
    GLOAD16(Ab + off0 + (size_t)(kt) * 64, &As[buf][dst0]);   \
    GLOAD16(Ab + off1 + (size_t)(kt) * 64, &As[buf][dst1]);   \
    GLOAD16(Bb + off0 + (size_t)(kt) * 64, &Bs[buf][dst0]);   \
    GLOAD16(Bb + off1 + (size_t)(kt) * 64, &Bs[buf][dst1]);   \
} while (0)

    v16i acc[2][2];
#pragma unroll
    for (int i = 0; i < 2; ++i)
#pragma unroll
        for (int j = 0; j < 2; ++j)
#pragma unroll
            for (int q = 0; q < 16; ++q) acc[i][j][q] = 0;

    // fragment reads (swizzled): row = base + (lane&31); key=(lane>>1)&3
    int arow = lane & 31, hi = lane >> 5, key = (lane >> 1) & 3;
    int rA0 = (wm * 64 + arow) * 64, rA1 = rA0 + 32 * 64;
    int rB0 = (wn * 64 + arow) * 64, rB1 = rB0 + 32 * 64;
    int c0 = (hi ^ key) * 16;          // kk=0
    int c1 = ((2 + hi) ^ key) * 16;    // kk=1

#define COMPUTE(bi) do {                                                         \
    lds_cptr ap = (lds_cptr)&As[bi][0];                                          \
    lds_cptr bp = (lds_cptr)&Bs[bi][0];                                          \
    v4i a0k0 = lds_read16(ap + rA0 + c0);                                        \
    v4i a1k0 = lds_read16(ap + rA1 + c0);                                        \
    v4i b0k0 = lds_read16(bp + rB0 + c0);                                        \
    v4i b1k0 = lds_read16(bp + rB1 + c0);                                        \
    v4i a0k1 = lds_read16(ap + rA0 + c1);                                        \
    v4i a1k1 = lds_read16(ap + rA1 + c1);                                        \
    v4i b0k1 = lds_read16(bp + rB0 + c1);                                        \
    v4i b1k1 = lds_read16(bp + rB1 + c1);                                        \
    asm volatile("s_waitcnt lgkmcnt(0)" ::: "memory");                           \
    __builtin_amdgcn_sched_barrier(0);                                           \
    acc[0][0] = MFMA_I8(a0k0, b0k0, acc[0][0]);                                  \
    acc[0][1] = MFMA_I8(a0k0, b1k0, acc[0][1]);                                  \
    acc[1][0] = MFMA_I8(a1k0, b0k0, acc[1][0]);                                  \
    acc[1][1] = MFMA_I8(a1k0, b1k0, acc[1][1]);                                  \
    acc[0][0] = MFMA_I8(a0k1, b0k1, acc[0][0]);                                  \
    acc[0][1] = MFMA_I8(a0k1, b1k1, acc[0][1]);                                  \
    acc[1][0] = MFMA_I8(a1k1, b0k1, acc[1][0]);                                  \
    acc[1][1] = MFMA_I8(a1k1, b1k1, acc[1][1]);                                  \
} while (0)

    // prologue: 2 tiles (8 loads/thread) in flight
    STAGE(0, 0);
    STAGE(1, 1);

    int cur = 0, nxt = 2;
    for (int kt = 0; kt < 14; ++kt) {
        asm volatile("s_waitcnt vmcnt(4)" ::: "memory");   // tile kt landed
        __builtin_amdgcn_s_barrier();
        __builtin_amdgcn_sched_barrier(0);
        STAGE(nxt, kt + 2);                                // refill to 8 outstanding
        COMPUTE(cur);
        cur = (cur == 2) ? 0 : cur + 1;
        nxt = (nxt == 2) ? 0 : nxt + 1;
    }
    // kt=14: tiles 14,15 in flight (8 loads) -> drain to 4 = tile 14 done
    asm volatile("s_waitcnt vmcnt(4)" ::: "memory");
    __builtin_amdgcn_s_barrier();
    __builtin_amdgcn_sched_barrier(0);
    COMPUTE(2);
    // kt=15
    asm volatile("s_waitcnt vmcnt(0)" ::: "memory");
    __builtin_amdgcn_s_barrier();
    __builtin_amdgcn_sched_barrier(0);
    COMPUTE(0);
#undef COMPUTE
#undef STAGE

    // epilogue: out = 7.5e-4 * (S' - 32*Rx + 66*Cy - 10813440)
    // C/D layout: col = lane&31, row = (q&3) + 8*(q>>2) + 4*(lane>>5)
    const float* rxp = rx + g * 1024 + m0 + wm * 64;
    const float* cyp = cy + b * 1024 + n0 + wn * 64;
    float* og = out + (size_t)g * 1048576 + (size_t)(m0 + wm * 64) * 1024 + n0 + wn * 64;
    int col = lane & 31, r4 = hi * 4;
#pragma unroll
    for (int fi = 0; fi < 2; ++fi)
#pragma unroll
        for (int fj = 0; fj < 2; ++fj) {
            int cc = fj * 32 + col;
            float cv = cyp[cc];
            v16i v = acc[fi][fj];
#pragma unroll
            for (int q = 0; q < 16; ++q) {
                int rl = (q & 3) + 8 * (q >> 2) + r4;
                float rxv = rxp[fi * 32 + rl];
                og[(size_t)(fi * 32 + rl) * 1024 + cc] =
                    7.5e-4f * ((float)v[q] - 32.0f * rxv + 66.0f * cv - 10813440.0f);
            }
        }
}

// ---- emergency fallback ----
__global__ void k_naive(const float* __restrict__ x, const float* __restrict__ y,
                        float* __restrict__ out) {
    int g = blockIdx.z, b = g & 7;
    int tx = threadIdx.x, ty = threadIdx.y;
    int m = blockIdx.y * 16 + ty, n = blockIdx.x * 16 + tx;
    __shared__ float a[16][17], bs[16][17];
    float s = 0.f;
    for (int kt = 0; kt < 64; ++kt) {
        a[ty][tx]  = x[(size_t)g * 1048576 + (size_t)m * 1024 + kt * 16 + tx];
        bs[ty][tx] = y[(size_t)b * 1048576 + (size_t)(kt * 16 + ty) * 1024 + n];
        __syncthreads();
#pragma unroll
        for (int j = 0; j < 16; ++j)
            s += ((a[ty][j] + 66.0f) * 0.03f) * ((bs[j][tx] - 160.0f) * 0.025f);
        __syncthreads();
    }
    out[(size_t)g * 1048576 + (size_t)m * 1024 + n] = s;
}

extern "C" void kernel_launch(void* const* d_in, const int* in_sizes, int n_in,
                              void* d_out, int out_size, void* d_ws, size_t ws_size,
                              hipStream_t stream) {
    const float* x = (const float*)d_in[0];
    const float* y = (const float*)d_in[1];
    float* out = (float*)d_out;

    const size_t CY_OFF = 0;                         // 32 KB
    const size_t RX_OFF = 32768;                     // 224 KB
    const size_t YT_OFF = 262144;                    // 8 MB
    const size_t XB_OFF = 262144 + 8388608ull;       // 56 MB
    const size_t NEED   = XB_OFF + 58720256ull;

    if (ws_size >= NEED) {
        float* cy         = (float*)((char*)d_ws + CY_OFF);
        float* rx         = (float*)((char*)d_ws + RX_OFF);
        unsigned char* yt = (unsigned char*)((char*)d_ws + YT_OFF);
        unsigned char* xb = (unsigned char*)((char*)d_ws + XB_OFF);
        hipMemsetAsync(cy, 0, 32768, stream);
        k_prep_x<<<14336, 256, 0, stream>>>(x, xb, rx);
        k_prep_y<<<2048, 256, 0, stream>>>(y, yt, cy);
        k_gemm<<<NG * 64, 256, 0, stream>>>(xb, yt, rx, cy, out);
    } else {
        dim3 grid(64, 64, NG), blk(16, 16);
        k_naive<<<grid, blk, 0, stream>>>(x, y, out);
    }
}

// Round 8
// 181.368 us; speedup vs baseline: 1.2458x; 1.0765x over previous
//
#include <hip/hip_runtime.h>
#include <cstdint>

// out[s,b,m,n] = sum_k (x+66)*0.03 * (y-160)*0.025,  S=7 B=8 M=K=N=1024
// y' = y-128; x, y' exact int8. i8 MFMA (int32-exact):
//   out = 7.5e-4 * ( S' - 32*Rx[m] + 66*Cy[n] - 10813440 ),  S' = sum x*y'
// GEMM: 256x256, 8 waves (2Mx4N), BK=64B, 3-ring LDS (96KB), m201-style 4-phase
// register-pipelined schedule: phase p reads phase p+1's fragments, MFMA consumes
// regs read in phase p-1; 1 raw barrier/phase; lgkmcnt(4) partial waits;
// vmcnt(3) only at tile seams; 1 gload_lds per phase (stage 2 tiles ahead).

#define NG 56

typedef int v4i  __attribute__((ext_vector_type(4)));
typedef int v16i __attribute__((ext_vector_type(16)));

#define GLOAD16(g, l) __builtin_amdgcn_global_load_lds( \
    (const __attribute__((address_space(1))) void*)(g), \
    (__attribute__((address_space(3))) void*)(l), 16, 0, 0)

#define MFMA_I8(a, b, c) __builtin_amdgcn_mfma_i32_32x32x32_i8(a, b, c, 0, 0, 0)

typedef __attribute__((address_space(3))) const unsigned char* lds_cptr;

__device__ __forceinline__ v4i lds_read16(lds_cptr p) {
    v4i d;
    asm volatile("ds_read_b128 %0, %1" : "=v"(d) : "v"(p));
    return d;
}

__device__ __forceinline__ unsigned pack4(float4 v, float& s) {
    s += (v.x + v.y) + (v.z + v.w);
    unsigned b0 = __float_as_uint(v.x + 8388736.0f);  // 2^23 + 128
    unsigned b1 = __float_as_uint(v.y + 8388736.0f);
    unsigned b2 = __float_as_uint(v.z + 8388736.0f);
    unsigned b3 = __float_as_uint(v.w + 8388736.0f);
    return ((b0 & 0xFFu) | ((b1 & 0xFFu) << 8) | ((b2 & 0xFFu) << 16) | ((b3 & 0xFFu) << 24))
           ^ 0x80808080u;
}

// ---- prepass 1: x -> i8 + row sums ----
__global__ __launch_bounds__(256) void k_prep_x(const float* __restrict__ x,
                                                unsigned char* __restrict__ xb,
                                                float* __restrict__ rx) {
    int row  = blockIdx.x * 4 + (threadIdx.x >> 6);
    int lane = threadIdx.x & 63;
    const float* src = x + (size_t)row * 1024;
    float s = 0.f;
#pragma unroll
    for (int it = 0; it < 4; ++it) {
        float4 v = *(const float4*)(src + it * 256 + lane * 4);
        unsigned p = pack4(v, s);
        *(unsigned*)&xb[(size_t)row * 1024 + it * 256 + lane * 4] = p;
    }
#pragma unroll
    for (int off = 32; off > 0; off >>= 1) s += __shfl_down(s, off);
    if (lane == 0) rx[row] = s;
}

// ---- prepass 2: y [b][k][n] -> yt [b][n][k] i8 (= y-128), + col sums Cy ----
__global__ __launch_bounds__(256) void k_prep_y(const float* __restrict__ y,
                                                unsigned char* __restrict__ yt,
                                                float* __restrict__ cy) {
    __shared__ float tile[64][65];
    __shared__ float csum[4][64];
    int b  = blockIdx.x >> 8;
    int t  = blockIdx.x & 255;
    int kt = (t >> 4) * 64, nt = (t & 15) * 64;
    int tx = threadIdx.x & 63;
    int ty = threadIdx.x >> 6;
    const float* src = y + ((size_t)b << 20) + (size_t)kt * 1024 + nt;
    float part = 0.f;
#pragma unroll
    for (int r = 0; r < 16; ++r) {
        int kk = r * 4 + ty;
        float v = src[(size_t)kk * 1024 + tx];
        tile[kk][tx] = v;
        part += v;
    }
    csum[ty][tx] = part;
    __syncthreads();
    if (threadIdx.x < 64) {
        float s = csum[0][tx] + csum[1][tx] + csum[2][tx] + csum[3][tx];
        atomicAdd(&cy[b * 1024 + nt + tx], s);
    }
    int ky = threadIdx.x & 15;
    int ny = threadIdx.x >> 4;
#pragma unroll
    for (int r = 0; r < 4; ++r) {
        int nn = r * 16 + ny;
        unsigned b0 = __float_as_uint(tile[ky * 4 + 0][nn] + 8388608.0f);
        unsigned b1 = __float_as_uint(tile[ky * 4 + 1][nn] + 8388608.0f);
        unsigned b2 = __float_as_uint(tile[ky * 4 + 2][nn] + 8388608.0f);
        unsigned b3 = __float_as_uint(tile[ky * 4 + 3][nn] + 8388608.0f);
        unsigned p = ((b0 & 0xFFu) | ((b1 & 0xFFu) << 8) | ((b2 & 0xFFu) << 16) |
                      ((b3 & 0xFFu) << 24)) ^ 0x80808080u;
        *(unsigned*)&yt[((size_t)b << 20) + (size_t)(nt + nn) * 1024 + kt + ky * 4] = p;
    }
}

// ---- GEMM: 256x256, 8 waves, 4-phase register-pipelined, i8 MFMA ----
__global__ __launch_bounds__(512, 2) void k_gemm(const unsigned char* __restrict__ xb,
                                                 const unsigned char* __restrict__ yt,
                                                 const float* __restrict__ rx,
                                                 const float* __restrict__ cy,
                                                 float* __restrict__ out) {
    __shared__ __align__(16) unsigned char As[3][256 * 64];
    __shared__ __align__(16) unsigned char Bs[3][256 * 64];

    int bid = blockIdx.x;                         // 896 = 8 * 112, bijective
    int wg  = (bid & 7) * 112 + (bid >> 3);
    int g   = wg >> 4;
    int t   = wg & 15;
    int m0  = (t >> 2) * 256, n0 = (t & 3) * 256;
    int b   = g & 7;

    int tid = threadIdx.x, lane = tid & 63, w = tid >> 6;
    int wm = w >> 2, wn = w & 3;                  // 2M x 4N wave grid

    const unsigned char* Ab = xb + (size_t)g * 1048576 + (size_t)m0 * 1024;
    const unsigned char* Bb = yt + ((size_t)b << 20) + (size_t)n0 * 1024;

    // staging map (verified R6): chunk cid -> LDS row cid>>2, phys chunk cid&3;
    // LDS (row,c) holds global (row, c ^ ((row>>1)&3)); linear dest.
    int srow   = tid >> 2;                        // 0..127 (g0); +128 (g1)
    int schunk = (tid & 3) ^ ((srow >> 1) & 3);
    size_t offA0 = (size_t)srow * 1024 + (size_t)schunk * 16;
    size_t offA1 = offA0 + 131072;                // rows +128, same key
    int dstA0 = (tid & ~63) * 16;
    int dstA1 = 8192 + (tid & ~63) * 16;

#define GLQ0(rs, kb) GLOAD16(Ab + offA0 + (size_t)(kb), &As[rs][dstA0])
#define GLQ1(rs, kb) GLOAD16(Ab + offA1 + (size_t)(kb), &As[rs][dstA1])
#define GLQ2(rs, kb) GLOAD16(Bb + offA0 + (size_t)(kb), &Bs[rs][dstA0])
#define GLQ3(rs, kb) GLOAD16(Bb + offA1 + (size_t)(kb), &Bs[rs][dstA1])

    v16i acc[4][2];
#pragma unroll
    for (int i = 0; i < 4; ++i)
#pragma unroll
        for (int j = 0; j < 2; ++j)
#pragma unroll
            for (int q = 0; q < 16; ++q) acc[i][j][q] = 0;

    // fragment addresses (verified R6): row = base + (lane&31); key=(lane>>1)&3
    int arow = lane & 31, hi = lane >> 5, key = (lane >> 1) & 3;
    int rA0 = (wm * 128 +  0 + arow) * 64;
    int rA1 = (wm * 128 + 32 + arow) * 64;
    int rA2 = (wm * 128 + 64 + arow) * 64;
    int rA3 = (wm * 128 + 96 + arow) * 64;
    int rB0 = (wn * 64 +  0 + arow) * 64;
    int rB1 = (wn * 64 + 32 + arow) * 64;
    int c0 = (hi ^ key) * 16;          // kk=0
    int c1 = ((2 + hi) ^ key) * 16;    // kk=1

    v4i cA0, cA1, cB0, cB1;            // phase-pipelined operand sets
    v4i nA0, nA1, nB0, nB1;

#define VM3 asm volatile("s_waitcnt vmcnt(3)" ::: "memory")
#define VM0 asm volatile("s_waitcnt vmcnt(0)" ::: "memory")
#define NOVM (void)0

// phase: [vm] barrier | read next-phase frags (ring RN, col CK, A rows RAa/RAb)
//        | 1 gload | lgkmcnt(4) | 4 MFMA on prev-read set (half HH)
#define PHASE(VMS, RN, CK, RAa, RAb, N0, N1, N2, N3, GLS, LGK, HH, C0_, C1_, C2_, C3_) do { \
    VMS;                                                                   \
    __builtin_amdgcn_s_barrier();                                          \
    __builtin_amdgcn_sched_barrier(0);                                     \
    { lds_cptr _ap = (lds_cptr)&As[RN][0];                                 \
      lds_cptr _bp = (lds_cptr)&Bs[RN][0];                                 \
      N0 = lds_read16(_ap + RAa + (CK));                                   \
      N1 = lds_read16(_ap + RAb + (CK));                                   \
      N2 = lds_read16(_bp + rB0 + (CK));                                   \
      N3 = lds_read16(_bp + rB1 + (CK)); }                                 \
    GLS;                                                                   \
    asm volatile("s_waitcnt lgkmcnt(" #LGK ")" ::: "memory");              \
    __builtin_amdgcn_sched_barrier(0);                                     \
    __builtin_amdgcn_s_setprio(1);                                         \
    acc[2*(HH)  ][0] = MFMA_I8(C0_, C2_, acc[2*(HH)  ][0]);                \
    acc[2*(HH)  ][1] = MFMA_I8(C0_, C3_, acc[2*(HH)  ][1]);                \
    acc[2*(HH)+1][0] = MFMA_I8(C1_, C2_, acc[2*(HH)+1][0]);                \
    acc[2*(HH)+1][1] = MFMA_I8(C1_, C3_, acc[2*(HH)+1][1]);                \
    __builtin_amdgcn_s_setprio(0);                                         \
} while (0)

// tile t: rings (rt = t%3, rn = (t+1)%3, rs = (t+2)%3); phases (kk,h):
// p0=(0,0) p1=(0,1) p2=(1,0) p3=(1,1); p reads p+1's frags; p3 reads t+1's p0.
#define TILE(rt, rn, rs, DOST, VMP3) do {                                                       \
    PHASE(NOVM, rt, c0, rA2, rA3, nA0,nA1,nB0,nB1, if (DOST) GLQ0(rs, kb);, 4, 0, cA0,cA1,cB0,cB1); \
    PHASE(NOVM, rt, c1, rA0, rA1, cA0,cA1,cB0,cB1, if (DOST) GLQ1(rs, kb);, 4, 1, nA0,nA1,nB0,nB1); \
    PHASE(NOVM, rt, c1, rA2, rA3, nA0,nA1,nB0,nB1, if (DOST) GLQ2(rs, kb);, 4, 0, cA0,cA1,cB0,cB1); \
    PHASE(VMP3, rn, c0, rA0, rA1, cA0,cA1,cB0,cB1, if (DOST) GLQ3(rs, kb);, 4, 1, nA0,nA1,nB0,nB1); \
} while (0)

    // prologue: stage tiles 0,1; wait tile 0; pre-read tile0 p0 frags
    GLQ0(0, 0);  GLQ1(0, 0);  GLQ2(0, 0);  GLQ3(0, 0);
    GLQ0(1, 64); GLQ1(1, 64); GLQ2(1, 64); GLQ3(1, 64);
    VM3; VM0;  // drain to 4 then... need tile0 only: vmcnt(4)
    // (VM0 above would over-drain; replace with explicit vmcnt(4))
    asm volatile("s_waitcnt vmcnt(4)" ::: "memory");
    __builtin_amdgcn_s_barrier();
    __builtin_amdgcn_sched_barrier(0);
    { lds_cptr _ap = (lds_cptr)&As[0][0];
      lds_cptr _bp = (lds_cptr)&Bs[0][0];
      cA0 = lds_read16(_ap + rA0 + c0);
      cA1 = lds_read16(_ap + rA1 + c0);
      cB0 = lds_read16(_bp + rB0 + c0);
      cB1 = lds_read16(_bp + rB1 + c0); }

    int kb = 128;   // byte-col of tile t+2
    for (int u = 0; u < 4; ++u) {       // tiles 0..11
        TILE(0, 1, 2, 1, VM3); kb += 64;
        TILE(1, 2, 0, 1, VM3); kb += 64;
        TILE(2, 0, 1, 1, VM3); kb += 64;
    }
    TILE(0, 1, 2, 1, VM3); kb += 64;    // t=12 (stages t14)
    TILE(1, 2, 0, 1, VM3); kb += 64;    // t=13 (stages t15)
    TILE(2, 0, 1, 0, VM0);              // t=14 (no stage; drain all at seam)
    // t=15 (ring 0), peeled: p0..p2 normal (no gloads), p3 = final MFMA
    PHASE(NOVM, 0, c0, rA2, rA3, nA0,nA1,nB0,nB1, NOVM;, 4, 0, cA0,cA1,cB0,cB1);
    PHASE(NOVM, 0, c1, rA0, rA1, cA0,cA1,cB0,cB1, NOVM;, 4, 1, nA0,nA1,nB0,nB1);
    PHASE(NOVM, 0, c1, rA2, rA3, nA0,nA1,nB0,nB1, NOVM;, 4, 0, cA0,cA1,cB0,cB1);
    __builtin_amdgcn_s_barrier();
    __builtin_amdgcn_sched_barrier(0);
    asm volatile("s_waitcnt lgkmcnt(0)" ::: "memory");
    __builtin_amdgcn_sched_barrier(0);
    acc[2][0] = MFMA_I8(nA0, nB0, acc[2][0]);
    acc[2][1] = MFMA_I8(nA0, nB1, acc[2][1]);
    acc[3][0] = MFMA_I8(nA1, nB0, acc[3][0]);
    acc[3][1] = MFMA_I8(nA1, nB1, acc[3][1]);
#undef TILE
#undef PHASE
#undef VM3
#undef VM0
#undef NOVM
#undef GLQ0
#undef GLQ1
#undef GLQ2
#undef GLQ3

    // epilogue: out = 7.5e-4 * (S' - 32*Rx + 66*Cy - 10813440)
    // C/D layout: col = lane&31, row = (q&3) + 8*(q>>2) + 4*(lane>>5)
    const float* rxp = rx + g * 1024 + m0 + wm * 128;
    const float* cyp = cy + b * 1024 + n0 + wn * 64;
    float* og = out + (size_t)g * 1048576 + (size_t)(m0 + wm * 128) * 1024 + n0 + wn * 64;
    int col = lane & 31, r4 = hi * 4;
#pragma unroll
    for (int fi = 0; fi < 4; ++fi)
#pragma unroll
        for (int fj = 0; fj < 2; ++fj) {
            int cc = fj * 32 + col;
            float cv = cyp[cc];
            v16i v = acc[fi][fj];
#pragma unroll
            for (int q = 0; q < 16; ++q) {
                int rl = (q & 3) + 8 * (q >> 2) + r4;
                float rxv = rxp[fi * 32 + rl];
                og[(size_t)(fi * 32 + rl) * 1024 + cc] =
                    7.5e-4f * ((float)v[q] - 32.0f * rxv + 66.0f * cv - 10813440.0f);
            }
        }
}

// ---- emergency fallback ----
__global__ void k_naive(const float* __restrict__ x, const float* __restrict__ y,
                        float* __restrict__ out) {
    int g = blockIdx.z, b = g & 7;
    int tx = threadIdx.x, ty = threadIdx.y;
    int m = blockIdx.y * 16 + ty, n = blockIdx.x * 16 + tx;
    __shared__ float a[16][17], bs[16][17];
    float s = 0.f;
    for (int kt = 0; kt < 64; ++kt) {
        a[ty][tx]  = x[(size_t)g * 1048576 + (size_t)m * 1024 + kt * 16 + tx];
        bs[ty][tx] = y[(size_t)b * 1048576 + (size_t)(kt * 16 + ty) * 1024 + n];
        __syncthreads();
#pragma unroll
        for (int j = 0; j < 16; ++j)
            s += ((a[ty][j] + 66.0f) * 0.03f) * ((bs[j][tx] - 160.0f) * 0.025f);
        __syncthreads();
    }
    out[(size_t)g * 1048576 + (size_t)m * 1024 + n] = s;
}

extern "C" void kernel_launch(void* const* d_in, const int* in_sizes, int n_in,
                              void* d_out, int out_size, void* d_ws, size_t ws_size,
                              hipStream_t stream) {
    const float* x = (const float*)d_in[0];
    const float* y = (const float*)d_in[1];
    float* out = (float*)d_out;

    const size_t CY_OFF = 0;                         // 32 KB
    const size_t RX_OFF = 32768;                     // 224 KB
    const size_t YT_OFF = 262144;                    // 8 MB
    const size_t XB_OFF = 262144 + 8388608ull;       // 56 MB
    const size_t NEED   = XB_OFF + 58720256ull;

    if (ws_size >= NEED) {
        float* cy         = (float*)((char*)d_ws + CY_OFF);
        float* rx         = (float*)((char*)d_ws + RX_OFF);
        unsigned char* yt = (unsigned char*)((char*)d_ws + YT_OFF);
        unsigned char* xb = (unsigned char*)((char*)d_ws + XB_OFF);
        hipMemsetAsync(cy, 0, 32768, stream);
        k_prep_x<<<14336, 256, 0, stream>>>(x, xb, rx);
        k_prep_y<<<2048, 256, 0, stream>>>(y, yt, cy);
        k_gemm<<<NG * 16, 512, 0, stream>>>(xb, yt, rx, cy, out);
    } else {
        dim3 grid(64, 64, NG), blk(16, 16);
        k_naive<<<grid, blk, 0, stream>>>(x, y, out);
    }
}

// Round 9
// 180.863 us; speedup vs baseline: 1.2493x; 1.0028x over previous
//
#include <hip/hip_runtime.h>
#include <cstdint>

// out[s,b,m,n] = sum_k (x+66)*0.03 * (y-160)*0.025,  S=7 B=8 M=K=N=1024
// y' = y-128; x, y' exact int8. i8 MFMA (int32-exact):
//   out = 7.5e-4 * ( S' - 32*Rx[m] + 66*Cy[n] - 10813440 ),  S' = sum x*y'
// GEMM: 256x256, 8 waves (2Mx4N), BK=64B, 3-ring LDS (96KB), m201-style 4-phase
// register-pipelined schedule: phase p reads phase p+1's fragments, MFMA consumes
// regs read in phase p-1; 1 raw barrier/phase; lgkmcnt(4) partial waits;
// vmcnt(3) only at tile seams; 1 gload_lds per phase (stage 2 tiles ahead).

#define NG 56

typedef int v4i  __attribute__((ext_vector_type(4)));
typedef int v16i __attribute__((ext_vector_type(16)));

#define GLOAD16(g, l) __builtin_amdgcn_global_load_lds( \
    (const __attribute__((address_space(1))) void*)(g), \
    (__attribute__((address_space(3))) void*)(l), 16, 0, 0)

#define MFMA_I8(a, b, c) __builtin_amdgcn_mfma_i32_32x32x32_i8(a, b, c, 0, 0, 0)

typedef __attribute__((address_space(3))) const unsigned char* lds_cptr;

__device__ __forceinline__ v4i lds_read16(lds_cptr p) {
    v4i d;
    asm volatile("ds_read_b128 %0, %1" : "=v"(d) : "v"(p));
    return d;
}

__device__ __forceinline__ unsigned pack4(float4 v, float& s) {
    s += (v.x + v.y) + (v.z + v.w);
    unsigned b0 = __float_as_uint(v.x + 8388736.0f);  // 2^23 + 128
    unsigned b1 = __float_as_uint(v.y + 8388736.0f);
    unsigned b2 = __float_as_uint(v.z + 8388736.0f);
    unsigned b3 = __float_as_uint(v.w + 8388736.0f);
    return ((b0 & 0xFFu) | ((b1 & 0xFFu) << 8) | ((b2 & 0xFFu) << 16) | ((b3 & 0xFFu) << 24))
           ^ 0x80808080u;
}

// ---- prepass 1: x -> i8 + row sums ----
__global__ __launch_bounds__(256) void k_prep_x(const float* __restrict__ x,
                                                unsigned char* __restrict__ xb,
                                                float* __restrict__ rx) {
    int row  = blockIdx.x * 4 + (threadIdx.x >> 6);
    int lane = threadIdx.x & 63;
    const float* src = x + (size_t)row * 1024;
    float s = 0.f;
#pragma unroll
    for (int it = 0; it < 4; ++it) {
        float4 v = *(const float4*)(src + it * 256 + lane * 4);
        unsigned p = pack4(v, s);
        *(unsigned*)&xb[(size_t)row * 1024 + it * 256 + lane * 4] = p;
    }
#pragma unroll
    for (int off = 32; off > 0; off >>= 1) s += __shfl_down(s, off);
    if (lane == 0) rx[row] = s;
}

// ---- prepass 2: y [b][k][n] -> yt [b][n][k] i8 (= y-128), + col sums Cy ----
__global__ __launch_bounds__(256) void k_prep_y(const float* __restrict__ y,
                                                unsigned char* __restrict__ yt,
                                                float* __restrict__ cy) {
    __shared__ float tile[64][65];
    __shared__ float csum[4][64];
    int b  = blockIdx.x >> 8;
    int t  = blockIdx.x & 255;
    int kt = (t >> 4) * 64, nt = (t & 15) * 64;
    int tx = threadIdx.x & 63;
    int ty = threadIdx.x >> 6;
    const float* src = y + ((size_t)b << 20) + (size_t)kt * 1024 + nt;
    float part = 0.f;
#pragma unroll
    for (int r = 0; r < 16; ++r) {
        int kk = r * 4 + ty;
        float v = src[(size_t)kk * 1024 + tx];
        tile[kk][tx] = v;
        part += v;
    }
    csum[ty][tx] = part;
    __syncthreads();
    if (threadIdx.x < 64) {
        float s = csum[0][tx] + csum[1][tx] + csum[2][tx] + csum[3][tx];
        atomicAdd(&cy[b * 1024 + nt + tx], s);
    }
    int ky = threadIdx.x & 15;
    int ny = threadIdx.x >> 4;
#pragma unroll
    for (int r = 0; r < 4; ++r) {
        int nn = r * 16 + ny;
        unsigned b0 = __float_as_uint(tile[ky * 4 + 0][nn] + 8388608.0f);
        unsigned b1 = __float_as_uint(tile[ky * 4 + 1][nn] + 8388608.0f);
        unsigned b2 = __float_as_uint(tile[ky * 4 + 2][nn] + 8388608.0f);
        unsigned b3 = __float_as_uint(tile[ky * 4 + 3][nn] + 8388608.0f);
        unsigned p = ((b0 & 0xFFu) | ((b1 & 0xFFu) << 8) | ((b2 & 0xFFu) << 16) |
                      ((b3 & 0xFFu) << 24)) ^ 0x80808080u;
        *(unsigned*)&yt[((size_t)b << 20) + (size_t)(nt + nn) * 1024 + kt + ky * 4] = p;
    }
}

// ---- GEMM: 256x256, 8 waves, 4-phase register-pipelined, i8 MFMA ----
__global__ __launch_bounds__(512, 2) void k_gemm(const unsigned char* __restrict__ xb,
                                                 const unsigned char* __restrict__ yt,
                                                 const float* __restrict__ rx,
                                                 const float* __restrict__ cy,
                                                 float* __restrict__ out) {
    __shared__ __align__(16) unsigned char As[3][256 * 64];
    __shared__ __align__(16) unsigned char Bs[3][256 * 64];

    int bid = blockIdx.x;                         // 896 = 8 * 112, bijective
    int wg  = (bid & 7) * 112 + (bid >> 3);
    int g   = wg >> 4;
    int t   = wg & 15;
    int m0  = (t >> 2) * 256, n0 = (t & 3) * 256;
    int b   = g & 7;

    int tid = threadIdx.x, lane = tid & 63, w = tid >> 6;
    int wm = w >> 2, wn = w & 3;                  // 2M x 4N wave grid

    const unsigned char* Ab = xb + (size_t)g * 1048576 + (size_t)m0 * 1024;
    const unsigned char* Bb = yt + ((size_t)b << 20) + (size_t)n0 * 1024;

    // staging map (verified R6): chunk cid -> LDS row cid>>2, phys chunk cid&3;
    // LDS (row,c) holds global (row, c ^ ((row>>1)&3)); linear dest.
    int srow   = tid >> 2;                        // 0..127 (g0); +128 (g1)
    int schunk = (tid & 3) ^ ((srow >> 1) & 3);
    size_t offA0 = (size_t)srow * 1024 + (size_t)schunk * 16;
    size_t offA1 = offA0 + 131072;                // rows +128, same key
    int dstA0 = (tid & ~63) * 16;
    int dstA1 = 8192 + (tid & ~63) * 16;

#define GLQ0(rs, kb) GLOAD16(Ab + offA0 + (size_t)(kb), &As[rs][dstA0])
#define GLQ1(rs, kb) GLOAD16(Ab + offA1 + (size_t)(kb), &As[rs][dstA1])
#define GLQ2(rs, kb) GLOAD16(Bb + offA0 + (size_t)(kb), &Bs[rs][dstA0])
#define GLQ3(rs, kb) GLOAD16(Bb + offA1 + (size_t)(kb), &Bs[rs][dstA1])

    v16i acc[4][2];
#pragma unroll
    for (int i = 0; i < 4; ++i)
#pragma unroll
        for (int j = 0; j < 2; ++j)
#pragma unroll
            for (int q = 0; q < 16; ++q) acc[i][j][q] = 0;

    // fragment addresses (verified R6): row = base + (lane&31); key=(lane>>1)&3
    int arow = lane & 31, hi = lane >> 5, key = (lane >> 1) & 3;
    int rA0 = (wm * 128 +  0 + arow) * 64;
    int rA1 = (wm * 128 + 32 + arow) * 64;
    int rA2 = (wm * 128 + 64 + arow) * 64;
    int rA3 = (wm * 128 + 96 + arow) * 64;
    int rB0 = (wn * 64 +  0 + arow) * 64;
    int rB1 = (wn * 64 + 32 + arow) * 64;
    int c0 = (hi ^ key) * 16;          // kk=0
    int c1 = ((2 + hi) ^ key) * 16;    // kk=1

    v4i cA0, cA1, cB0, cB1;            // phase-pipelined operand sets
    v4i nA0, nA1, nB0, nB1;

#define VM3 asm volatile("s_waitcnt vmcnt(3)" ::: "memory")
#define VM0 asm volatile("s_waitcnt vmcnt(0)" ::: "memory")
#define NOVM (void)0

// phase: [vm] barrier | read next-phase frags (ring RN, col CK, A rows RAa/RAb)
//        | 1 gload | lgkmcnt(4) | 4 MFMA on prev-read set (half HH)
#define PHASE(VMS, RN, CK, RAa, RAb, N0, N1, N2, N3, GLS, LGK, HH, C0_, C1_, C2_, C3_) do { \
    VMS;                                                                   \
    __builtin_amdgcn_s_barrier();                                          \
    __builtin_amdgcn_sched_barrier(0);                                     \
    { lds_cptr _ap = (lds_cptr)&As[RN][0];                                 \
      lds_cptr _bp = (lds_cptr)&Bs[RN][0];                                 \
      N0 = lds_read16(_ap + RAa + (CK));                                   \
      N1 = lds_read16(_ap + RAb + (CK));                                   \
      N2 = lds_read16(_bp + rB0 + (CK));                                   \
      N3 = lds_read16(_bp + rB1 + (CK)); }                                 \
    GLS;                                                                   \
    asm volatile("s_waitcnt lgkmcnt(" #LGK ")" ::: "memory");              \
    __builtin_amdgcn_sched_barrier(0);                                     \
    __builtin_amdgcn_s_setprio(1);                                         \
    acc[2*(HH)  ][0] = MFMA_I8(C0_, C2_, acc[2*(HH)  ][0]);                \
    acc[2*(HH)  ][1] = MFMA_I8(C0_, C3_, acc[2*(HH)  ][1]);                \
    acc[2*(HH)+1][0] = MFMA_I8(C1_, C2_, acc[2*(HH)+1][0]);                \
    acc[2*(HH)+1][1] = MFMA_I8(C1_, C3_, acc[2*(HH)+1][1]);                \
    __builtin_amdgcn_s_setprio(0);                                         \
} while (0)

// tile t: rings (rt = t%3, rn = (t+1)%3, rs = (t+2)%3); phases (kk,h):
// p0=(0,0) p1=(0,1) p2=(1,0) p3=(1,1); p reads p+1's frags; p3 reads t+1's p0.
#define TILE(rt, rn, rs, DOST, VMP3) do {                                                       \
    PHASE(NOVM, rt, c0, rA2, rA3, nA0,nA1,nB0,nB1, if (DOST) GLQ0(rs, kb);, 4, 0, cA0,cA1,cB0,cB1); \
    PHASE(NOVM, rt, c1, rA0, rA1, cA0,cA1,cB0,cB1, if (DOST) GLQ1(rs, kb);, 4, 1, nA0,nA1,nB0,nB1); \
    PHASE(NOVM, rt, c1, rA2, rA3, nA0,nA1,nB0,nB1, if (DOST) GLQ2(rs, kb);, 4, 0, cA0,cA1,cB0,cB1); \
    PHASE(VMP3, rn, c0, rA0, rA1, cA0,cA1,cB0,cB1, if (DOST) GLQ3(rs, kb);, 4, 1, nA0,nA1,nB0,nB1); \
} while (0)

    // prologue: stage tiles 0,1; wait tile 0; pre-read tile0 p0 frags
    GLQ0(0, 0);  GLQ1(0, 0);  GLQ2(0, 0);  GLQ3(0, 0);
    GLQ0(1, 64); GLQ1(1, 64); GLQ2(1, 64); GLQ3(1, 64);
    VM3; VM0;  // drain to 4 then... need tile0 only: vmcnt(4)
    // (VM0 above would over-drain; replace with explicit vmcnt(4))
    asm volatile("s_waitcnt vmcnt(4)" ::: "memory");
    __builtin_amdgcn_s_barrier();
    __builtin_amdgcn_sched_barrier(0);
    { lds_cptr _ap = (lds_cptr)&As[0][0];
      lds_cptr _bp = (lds_cptr)&Bs[0][0];
      cA0 = lds_read16(_ap + rA0 + c0);
      cA1 = lds_read16(_ap + rA1 + c0);
      cB0 = lds_read16(_bp + rB0 + c0);
      cB1 = lds_read16(_bp + rB1 + c0); }

    int kb = 128;   // byte-col of tile t+2
    for (int u = 0; u < 4; ++u) {       // tiles 0..11
        TILE(0, 1, 2, 1, VM3); kb += 64;
        TILE(1, 2, 0, 1, VM3); kb += 64;
        TILE(2, 0, 1, 1, VM3); kb += 64;
    }
    TILE(0, 1, 2, 1, VM3); kb += 64;    // t=12 (stages t14)
    TILE(1, 2, 0, 1, VM3); kb += 64;    // t=13 (stages t15)
    TILE(2, 0, 1, 0, VM0);              // t=14 (no stage; drain all at seam)
    // t=15 (ring 0), peeled: p0..p2 normal (no gloads), p3 = final MFMA
    PHASE(NOVM, 0, c0, rA2, rA3, nA0,nA1,nB0,nB1, NOVM;, 4, 0, cA0,cA1,cB0,cB1);
    PHASE(NOVM, 0, c1, rA0, rA1, cA0,cA1,cB0,cB1, NOVM;, 4, 1, nA0,nA1,nB0,nB1);
    PHASE(NOVM, 0, c1, rA2, rA3, nA0,nA1,nB0,nB1, NOVM;, 4, 0, cA0,cA1,cB0,cB1);
    __builtin_amdgcn_s_barrier();
    __builtin_amdgcn_sched_barrier(0);
    asm volatile("s_waitcnt lgkmcnt(0)" ::: "memory");
    __builtin_amdgcn_sched_barrier(0);
    acc[2][0] = MFMA_I8(nA0, nB0, acc[2][0]);
    acc[2][1] = MFMA_I8(nA0, nB1, acc[2][1]);
    acc[3][0] = MFMA_I8(nA1, nB0, acc[3][0]);
    acc[3][1] = MFMA_I8(nA1, nB1, acc[3][1]);
#undef TILE
#undef PHASE
#undef VM3
#undef VM0
#undef NOVM
#undef GLQ0
#undef GLQ1
#undef GLQ2
#undef GLQ3

    // epilogue: out = 7.5e-4 * (S' - 32*Rx + 66*Cy - 10813440)
    // C/D layout: col = lane&31, row = (q&3) + 8*(q>>2) + 4*(lane>>5)
    const float* rxp = rx + g * 1024 + m0 + wm * 128;
    const float* cyp = cy + b * 1024 + n0 + wn * 64;
    float* og = out + (size_t)g * 1048576 + (size_t)(m0 + wm * 128) * 1024 + n0 + wn * 64;
    int col = lane & 31, r4 = hi * 4;
#pragma unroll
    for (int fi = 0; fi < 4; ++fi)
#pragma unroll
        for (int fj = 0; fj < 2; ++fj) {
            int cc = fj * 32 + col;
            float cv = cyp[cc];
            v16i v = acc[fi][fj];
#pragma unroll
            for (int q = 0; q < 16; ++q) {
                int rl = (q & 3) + 8 * (q >> 2) + r4;
                float rxv = rxp[fi * 32 + rl];
                og[(size_t)(fi * 32 + rl) * 1024 + cc] =
                    7.5e-4f * ((float)v[q] - 32.0f * rxv + 66.0f * cv - 10813440.0f);
            }
        }
}

// ---- emergency fallback ----
__global__ void k_naive(const float* __restrict__ x, const float* __restrict__ y,
                        float* __restrict__ out) {
    int g = blockIdx.z, b = g & 7;
    int tx = threadIdx.x, ty = threadIdx.y;
    int m = blockIdx.y * 16 + ty, n = blockIdx.x * 16 + tx;
    __shared__ float a[16][17], bs[16][17];
    float s = 0.f;
    for (int kt = 0; kt < 64; ++kt) {
        a[ty][tx]  = x[(size_t)g * 1048576 + (size_t)m * 1024 + kt * 16 + tx];
        bs[ty][tx] = y[(size_t)b * 1048576 + (size_t)(kt * 16 + ty) * 1024 + n];
        __syncthreads();
#pragma unroll
        for (int j = 0; j < 16; ++j)
            s += ((a[ty][j] + 66.0f) * 0.03f) * ((bs[j][tx] - 160.0f) * 0.025f);
        __syncthreads();
    }
    out[(size_t)g * 1048576 + (size_t)m * 1024 + n] = s;
}

extern "C" void kernel_launch(void* const* d_in, const int* in_sizes, int n_in,
                              void* d_out, int out_size, void* d_ws, size_t ws_size,
                              hipStream_t stream) {
    const float* x = (const float*)d_in[0];
    const float* y = (const float*)d_in[1];
    float* out = (float*)d_out;

    const size_t CY_OFF = 0;                         // 32 KB
    const size_t RX_OFF = 32768;                     // 224 KB
    const size_t YT_OFF = 262144;                    // 8 MB
    const size_t XB_OFF = 262144 + 8388608ull;       // 56 MB
    const size_t NEED   = XB_OFF + 58720256ull;

    if (ws_size >= NEED) {
        float* cy         = (float*)((char*)d_ws + CY_OFF);
        float* rx         = (float*)((char*)d_ws + RX_OFF);
        unsigned char* yt = (unsigned char*)((char*)d_ws + YT_OFF);
        unsigned char* xb = (unsigned char*)((char*)d_ws + XB_OFF);
        hipMemsetAsync(cy, 0, 32768, stream);
        k_prep_x<<<14336, 256, 0, stream>>>(x, xb, rx);
        k_prep_y<<<2048, 256, 0, stream>>>(y, yt, cy);
        k_gemm<<<NG * 16, 512, 0, stream>>>(xb, yt, rx, cy, out);
    } else {
        dim3 grid(64, 64, NG), blk(16, 16);
        k_naive<<<grid, blk, 0, stream>>>(x, y, out);
    }
}